// Round 10
// baseline (405.064 us; speedup 1.0000x reference)
//
#include <hip/hip_runtime.h>
#include <cstddef>
#include <cstdint>

#define NN 20000

typedef short frag16 __attribute__((ext_vector_type(8)));
typedef float f32x4 __attribute__((ext_vector_type(4)));

__device__ inline unsigned short f32_to_bf16(float f) {
    uint32_t u = __float_as_uint(f);
    u += 0x7FFFu + ((u >> 16) & 1u);
    return (unsigned short)(u >> 16);
}

__device__ inline void dec8_add(uint4 v, float* a) {
    a[0] += __uint_as_float(v.x << 16);
    a[1] += __uint_as_float(v.x & 0xffff0000u);
    a[2] += __uint_as_float(v.y << 16);
    a[3] += __uint_as_float(v.y & 0xffff0000u);
    a[4] += __uint_as_float(v.z << 16);
    a[5] += __uint_as_float(v.z & 0xffff0000u);
    a[6] += __uint_as_float(v.w << 16);
    a[7] += __uint_as_float(v.w & 0xffff0000u);
}

// ===================== fused prep (R4 layout: measured best) ======================
__global__ __launch_bounds__(256) void prep(
    const float* __restrict__ nodes, const float* __restrict__ x,
    const float* __restrict__ gcn_W, const float* __restrict__ bp,
    const int* __restrict__ src, const int* __restrict__ dst,
    unsigned short* __restrict__ nsum16, unsigned short* __restrict__ WT,
    float* __restrict__ Tf, float* __restrict__ cvec,
    int* __restrict__ cnt, int* __restrict__ csr, int E)
{
    __shared__ __align__(16) char shmem[8704];
    const int blk = blockIdx.x, tid = threadIdx.x;

    if (blk < 64) {                          // ---- T section (fp32, dbuf loads) ----
        float* As = (float*)shmem;
        float* Bs = As + 1024;
        int t = blk;
        int b = t >> 5, rem = t & 31;
        int s0 = (rem >> 3) * 64, f0 = (rem & 7) * 64;
        const float* W1 = gcn_W;
        const float* xb = x + (size_t)b * 256 * 512;
        int kk = tid >> 4, c4 = (tid & 15) << 2;
        int tm = tid >> 4, tn = tid & 15;
        float acc[4][4] = {};
        float4 av = *(const float4*)(W1 + (size_t)kk * 256 + s0 + c4);
        float4 bv = *(const float4*)(xb + (size_t)kk * 512 + f0 + c4);
        for (int k0 = 0; k0 < 256; k0 += 16) {
            __syncthreads();
            *(float4*)&As[kk * 64 + c4] = av;
            *(float4*)&Bs[kk * 64 + c4] = bv;
            __syncthreads();
            if (k0 + 16 < 256) {             // prefetch next tile under compute
                av = *(const float4*)(W1 + (size_t)(k0 + 16 + kk) * 256 + s0 + c4);
                bv = *(const float4*)(xb + (size_t)(k0 + 16 + kk) * 512 + f0 + c4);
            }
            #pragma unroll
            for (int k = 0; k < 16; ++k) {
                float a[4], bb[4];
                *(float4*)a  = *(const float4*)&As[k * 64 + (tm << 2)];
                *(float4*)bb = *(const float4*)&Bs[k * 64 + (tn << 2)];
                #pragma unroll
                for (int i = 0; i < 4; ++i)
                    #pragma unroll
                    for (int j = 0; j < 4; ++j) acc[i][j] += a[i] * bb[j];
            }
        }
        #pragma unroll
        for (int i = 0; i < 4; ++i) {
            int row = b * 256 + s0 + (tm << 2) + i;
            *(float4*)(Tf + (size_t)row * 512 + f0 + (tn << 2)) =
                make_float4(acc[i][0], acc[i][1], acc[i][2], acc[i][3]);
        }
    } else if (blk < 96) {                   // ---- WT transpose (l=1,2) ----
        unsigned short (*tsh)[68] = (unsigned short(*)[68])shmem;
        int t = blk - 64;
        int l = t >> 4, rem = t & 15;
        int c0 = (rem & 3) * 64, r0 = (rem >> 2) * 64;
        const float* inp = gcn_W + (size_t)(l + 1) * 65536;
        unsigned short* outp = WT + (size_t)l * 65536;
        int tx = tid & 15, ty = tid >> 4;
        #pragma unroll
        for (int rr = 0; rr < 4; ++rr) {
            int r = ty * 4 + rr;
            float4 v = *(const float4*)(inp + (size_t)(r0 + r) * 256 + c0 + tx * 4);
            tsh[tx * 4 + 0][r] = f32_to_bf16(v.x);
            tsh[tx * 4 + 1][r] = f32_to_bf16(v.y);
            tsh[tx * 4 + 2][r] = f32_to_bf16(v.z);
            tsh[tx * 4 + 3][r] = f32_to_bf16(v.w);
        }
        __syncthreads();
        #pragma unroll
        for (int cc = 0; cc < 4; ++cc) {
            int c = ty * 4 + cc;
            ushort4 o = *(ushort4*)&tsh[c][tx * 4];
            *(ushort4*)(outp + (size_t)(c0 + c) * 256 + r0 + tx * 4) = o;
        }
    } else if (blk < 224) {                  // ---- cvec ----
        int row = (blk - 96) * 4 + (tid >> 6);
        int lane = tid & 63;
        const float* xr = x + (size_t)row * 512;
        float s = 0.f;
        #pragma unroll
        for (int k = 0; k < 512; k += 64) s += xr[k + lane] * bp[k + lane];
        #pragma unroll
        for (int off = 32; off; off >>= 1) s += __shfl_down(s, off);
        if (lane == 0) cvec[row] = 2.0f * s;
    } else if (blk < 224 + 2512) {           // ---- nsum, 16 shorts/thread ----
        int g = (blk - 224) * 256 + tid;
        int n = g >> 5, c = (g & 31) << 4;
        uint4 o0, o1;
        if (n < NN) {
            const float* r0 = nodes + (size_t)n * 1024 + c;
            const float* r1 = r0 + 512;
            float4 a0 = *(const float4*)(r0 + 0),  a1 = *(const float4*)(r0 + 4);
            float4 a2 = *(const float4*)(r0 + 8),  a3 = *(const float4*)(r0 + 12);
            float4 b0 = *(const float4*)(r1 + 0),  b1 = *(const float4*)(r1 + 4);
            float4 b2 = *(const float4*)(r1 + 8),  b3 = *(const float4*)(r1 + 12);
            o0.x = ((uint32_t)f32_to_bf16(a0.y + b0.y) << 16) | f32_to_bf16(a0.x + b0.x);
            o0.y = ((uint32_t)f32_to_bf16(a0.w + b0.w) << 16) | f32_to_bf16(a0.z + b0.z);
            o0.z = ((uint32_t)f32_to_bf16(a1.y + b1.y) << 16) | f32_to_bf16(a1.x + b1.x);
            o0.w = ((uint32_t)f32_to_bf16(a1.w + b1.w) << 16) | f32_to_bf16(a1.z + b1.z);
            o1.x = ((uint32_t)f32_to_bf16(a2.y + b2.y) << 16) | f32_to_bf16(a2.x + b2.x);
            o1.y = ((uint32_t)f32_to_bf16(a2.w + b2.w) << 16) | f32_to_bf16(a2.z + b2.z);
            o1.z = ((uint32_t)f32_to_bf16(a3.y + b3.y) << 16) | f32_to_bf16(a3.x + b3.x);
            o1.w = ((uint32_t)f32_to_bf16(a3.w + b3.w) << 16) | f32_to_bf16(a3.z + b3.z);
        } else {
            o0 = make_uint4(0, 0, 0, 0); o1 = o0;
        }
        *(uint4*)(nsum16 + (size_t)n * 512 + c) = o0;
        *(uint4*)(nsum16 + (size_t)n * 512 + c + 8) = o1;
    } else {                                 // ---- count + CSR fill ----
        int e = (blk - 2736) * 256 + tid;
        if (e < E) {
            int d = dst[e];
            int pos = atomicAdd(&cnt[d], 1);
            if (pos < 64) csr[(d << 6) + pos] = src[e];
        }
    }
}

// ===================== mid: U = T @ Wp (bf16 out) + cb2 = W1^T . cvec ==============
// (R4 version: 64x64 tiles, 66 blocks — the 32x32 rewrite regressed in R8/R9)
__global__ __launch_bounds__(256) void mid(
    const float* __restrict__ Tf, const float* __restrict__ Wp,
    const float* __restrict__ gcn_W, const float* __restrict__ cvec,
    unsigned short* __restrict__ Ub, float* __restrict__ cb2)
{
    const int blk = blockIdx.x, tid = threadIdx.x;
    if (blk >= 64) {
        int idx = (blk - 64) * 256 + tid;
        int b = idx >> 8, s = idx & 255;
        float sum = 0.f;
        for (int sp = 0; sp < 256; ++sp)
            sum += gcn_W[(size_t)sp * 256 + s] * cvec[b * 256 + sp];
        cb2[idx] = sum;
        return;
    }
    __shared__ float As[16][68];
    __shared__ float Bs[16][64];
    int bm = (blk >> 3) * 64, bn = (blk & 7) * 64;
    int arow = tid >> 2, acol = (tid & 3) << 2;
    int brow = tid >> 4, bcol = (tid & 15) << 2;
    int tm = tid >> 4, tn = tid & 15;
    float acc[4][4] = {};
    float4 av = *(const float4*)(Tf + (size_t)(bm + arow) * 512 + acol);
    float4 bv = *(const float4*)(Wp + (size_t)brow * 512 + bn + bcol);
    for (int k0 = 0; k0 < 512; k0 += 16) {
        __syncthreads();
        As[acol + 0][arow] = av.x; As[acol + 1][arow] = av.y;
        As[acol + 2][arow] = av.z; As[acol + 3][arow] = av.w;
        *(float4*)&Bs[brow][bcol] = bv;
        __syncthreads();
        if (k0 + 16 < 512) {                 // prefetch next tile under compute
            av = *(const float4*)(Tf + (size_t)(bm + arow) * 512 + k0 + 16 + acol);
            bv = *(const float4*)(Wp + (size_t)(k0 + 16 + brow) * 512 + bn + bcol);
        }
        #pragma unroll
        for (int k = 0; k < 16; ++k) {
            float a[4], b[4];
            *(float4*)a = *(const float4*)&As[k][tm << 2];
            *(float4*)b = *(const float4*)&Bs[k][tn << 2];
            #pragma unroll
            for (int i = 0; i < 4; ++i)
                #pragma unroll
                for (int j = 0; j < 4; ++j) acc[i][j] += a[i] * b[j];
        }
    }
    #pragma unroll
    for (int i = 0; i < 4; ++i) {
        int row = bm + (tm << 2) + i;
        ushort4 o;
        o.x = f32_to_bf16(acc[i][0]); o.y = f32_to_bf16(acc[i][1]);
        o.z = f32_to_bf16(acc[i][2]); o.w = f32_to_bf16(acc[i][3]);
        *(ushort4*)(Ub + (size_t)row * 512 + bn + (tn << 2)) = o;
    }
}

// ===================== bf16 MFMA GEMM — DIRECT (no LDS, no barriers) ==============
// C = A[M,K] @ BT[N,K]^T, bf16 in/out, fp32 accum. A (~20MB) is L2/L3-resident,
// BT (<=0.5MB) is L2-hot -> load MFMA fragments straight global->register:
// lane (r16,q16) reads 16B at row(bm+wm+i*16+r16), col k0+q16*8. A wave's fragment
// load = 16 rows x 64 contiguous B. No __syncthreads, no vmcnt(0) drains; waves
// fully independent; unroll-2 pipelines next-iter loads under current MFMAs.
// 128x64 tile, 4 waves: wave does 64x32 via acc[4][2].
// mode 1: C[m*512+n] = (acc + cb2[n]) * rsqrt(cnt[m]+1)   (m = node)
// mode 2: N=256; b2 = m>=NN, node=m-b2*NN; C[node*512+(b2<<8)+n] = acc*rsqrt(cnt+1)
__global__ __launch_bounds__(256) void mgemm(
    const unsigned short* __restrict__ A, const unsigned short* __restrict__ BT,
    int K, int N, int mode,
    const float* __restrict__ cb2, const int* __restrict__ cnt,
    unsigned short* __restrict__ C)
{
    const int bm = blockIdx.y * 128, bn = blockIdx.x * 64;
    const int tid = threadIdx.x;
    const int lane = tid & 63, w = tid >> 6;
    const int wm = (w >> 1) << 6, wn = (w & 1) << 5;
    const int r16 = lane & 15, q16 = lane >> 4;

    const unsigned short* Ap = A  + (size_t)(bm + wm + r16) * K + (q16 << 3);
    const unsigned short* Bp = BT + (size_t)(bn + wn + r16) * K + (q16 << 3);
    const size_t a16 = (size_t)16 * K;         // 16-row stride

    f32x4 acc[4][2] = {};

    #pragma unroll 2
    for (int k0 = 0; k0 < K; k0 += 32) {
        frag16 af[4], bf[2];
        af[0] = *(const frag16*)(Ap + k0);
        af[1] = *(const frag16*)(Ap + a16 + k0);
        af[2] = *(const frag16*)(Ap + 2 * a16 + k0);
        af[3] = *(const frag16*)(Ap + 3 * a16 + k0);
        bf[0] = *(const frag16*)(Bp + k0);
        bf[1] = *(const frag16*)(Bp + a16 + k0);
        #pragma unroll
        for (int i = 0; i < 4; ++i)
            #pragma unroll
            for (int j = 0; j < 2; ++j)
                acc[i][j] = __builtin_amdgcn_mfma_f32_16x16x32_bf16(af[i], bf[j], acc[i][j], 0, 0, 0);
    }

    // C/D layout: col = lane&15 (r16), row = q16*4 + reg
    #pragma unroll
    for (int i = 0; i < 4; ++i) {
        #pragma unroll
        for (int rg = 0; rg < 4; ++rg) {
            int m = bm + wm + i * 16 + (q16 << 2) + rg;
            float sc;
            int b2 = 0, node = m;
            if (mode == 1) {
                int nc = m > NN - 1 ? NN - 1 : m;
                sc = rsqrtf((float)cnt[nc] + 1.0f);
            } else {
                b2 = m >= NN;
                node = m - b2 * NN;
                int nc = node > NN - 1 ? NN - 1 : node;
                sc = rsqrtf((float)cnt[nc] + 1.0f);
                if (node > 20095) node = 20095;
            }
            #pragma unroll
            for (int j = 0; j < 2; ++j) {
                int n = bn + wn + j * 16 + r16;
                if (mode == 1) {
                    float v = (acc[i][j][rg] + cb2[n]) * sc;
                    C[(size_t)m * 512 + n] = f32_to_bf16(v);
                } else {
                    float v = acc[i][j][rg] * sc;
                    C[(size_t)node * 512 + (b2 << 8) + n] = f32_to_bf16(v);
                }
            }
        }
    }
}

// ===================== GCN aggregation (R4: XCD-sliced, LDS-csr, 8-deep) ==========
__global__ __launch_bounds__(256) void aggregate_x(
    const unsigned short* __restrict__ hw, const int* __restrict__ cnt,
    const int* __restrict__ csr, const float* __restrict__ bias,
    unsigned short* __restrict__ hout,
    const float* __restrict__ w_bp, float* __restrict__ pout)
{
    __shared__ int sidx[2048];
    __shared__ int sdeg[32];
    const int s  = blockIdx.x & 7;             // slice 0..7
    const int nb = blockIdx.x >> 3;            // node block 0..624
    const int tid = threadIdx.x;
    const int g = tid >> 3;                    // group 0..31
    const int j = tid & 7;                     // lane in group
    const int n = nb * 32 + g;                 // node 0..19999

    {   // coalesced CSR block preload: 2048 ints, 8 per thread
        const int4* cp = (const int4*)(csr + ((size_t)nb << 11));
        int4 v0 = cp[tid * 2];
        int4 v1 = cp[tid * 2 + 1];
        *(int4*)&sidx[tid * 8]     = v0;
        *(int4*)&sidx[tid * 8 + 4] = v1;
        if (tid < 32) {
            int d = cnt[nb * 32 + tid];
            sdeg[tid] = d > 64 ? 64 : d;
        }
    }
    __syncthreads();

    const unsigned short* rowp = hw + (s << 6) + (j << 3);  // 16B/lane, 128B/group
    const int deg = sdeg[g];
    const int* gi = sidx + (g << 6);

    float acc[8] = {};
    dec8_add(*(const uint4*)(rowp + (size_t)n * 512), acc);   // self loop

    int e = 0;
    for (; e + 8 <= deg; e += 8) {
        int s0 = gi[e + 0], s1 = gi[e + 1], s2 = gi[e + 2], s3 = gi[e + 3];
        int s4 = gi[e + 4], s5 = gi[e + 5], s6 = gi[e + 6], s7 = gi[e + 7];
        uint4 u0 = *(const uint4*)(rowp + (size_t)s0 * 512);
        uint4 u1 = *(const uint4*)(rowp + (size_t)s1 * 512);
        uint4 u2 = *(const uint4*)(rowp + (size_t)s2 * 512);
        uint4 u3 = *(const uint4*)(rowp + (size_t)s3 * 512);
        uint4 u4 = *(const uint4*)(rowp + (size_t)s4 * 512);
        uint4 u5 = *(const uint4*)(rowp + (size_t)s5 * 512);
        uint4 u6 = *(const uint4*)(rowp + (size_t)s6 * 512);
        uint4 u7 = *(const uint4*)(rowp + (size_t)s7 * 512);
        dec8_add(u0, acc); dec8_add(u1, acc); dec8_add(u2, acc); dec8_add(u3, acc);
        dec8_add(u4, acc); dec8_add(u5, acc); dec8_add(u6, acc); dec8_add(u7, acc);
    }
    for (; e < deg; ++e) {
        dec8_add(*(const uint4*)(rowp + (size_t)gi[e] * 512), acc);
    }

    float dn = rsqrtf((float)deg + 1.0f);
    int colb = ((s & 3) << 6) + (j << 3);      // column within batch, 0..248
    float bl[8];
    *(float4*)&bl[0] = *(const float4*)(bias + colb);
    *(float4*)&bl[4] = *(const float4*)(bias + colb + 4);
    float v[8];
    #pragma unroll
    for (int t = 0; t < 8; ++t) {
        v[t] = fmaf(dn, acc[t], bl[t]);
        v[t] = v[t] > 0.f ? v[t] : 0.01f * v[t];
    }

    if (hout) {
        int b = s >> 2;
        uint4 o;
        o.x = ((uint32_t)f32_to_bf16(v[1]) << 16) | f32_to_bf16(v[0]);
        o.y = ((uint32_t)f32_to_bf16(v[3]) << 16) | f32_to_bf16(v[2]);
        o.z = ((uint32_t)f32_to_bf16(v[5]) << 16) | f32_to_bf16(v[4]);
        o.w = ((uint32_t)f32_to_bf16(v[7]) << 16) | f32_to_bf16(v[6]);
        *(uint4*)(hout + ((size_t)(b * NN + n)) * 256 + colb) = o;
    } else {
        float w4[8];
        *(float4*)&w4[0] = *(const float4*)(w_bp + colb);
        *(float4*)&w4[4] = *(const float4*)(w_bp + colb + 4);
        float sum = 0.f;
        #pragma unroll
        for (int t = 0; t < 8; ++t) sum += v[t] * w4[t];
        sum += __shfl_xor(sum, 1);
        sum += __shfl_xor(sum, 2);
        sum += __shfl_xor(sum, 4);
        if (j == 0) pout[s * NN + n] = sum;
    }
}

// sum the 4 slice partials per (batch, node) and add bias
__global__ __launch_bounds__(256) void finishk(
    const float* __restrict__ pout, const float* __restrict__ b_bp,
    float* __restrict__ out)
{
    int i = blockIdx.x * 256 + threadIdx.x;
    if (i < 2 * NN) {
        int b = i >= NN;
        int n = i - b * NN;
        const float* p = pout + b * 4 * NN + n;
        out[i] = b_bp[0] + p[0] + p[NN] + p[2 * NN] + p[3 * NN];
    }
}

extern "C" void kernel_launch(void* const* d_in, const int* in_sizes, int n_in,
                              void* d_out, int out_size, void* d_ws, size_t ws_size,
                              hipStream_t stream) {
    const float* x     = (const float*)d_in[0];
    const float* nodes = (const float*)d_in[1];
    const int*   eidx  = (const int*)d_in[2];
    const float* Wp    = (const float*)d_in[3];
    const float* bp    = (const float*)d_in[4];
    const float* gcn_W = (const float*)d_in[5];
    const float* gcn_b = (const float*)d_in[6];
    const float* w_bp  = (const float*)d_in[7];
    const float* b_bp  = (const float*)d_in[8];
    const int E = in_sizes[2] / 2;

    char* w = (char*)d_ws;
    auto alloc = [&](size_t bytes) { char* p = w; w += (bytes + 255) & ~(size_t)255; return p; };
    unsigned short* nsum16 = (unsigned short*)alloc((size_t)20096 * 512 * 2);
    unsigned short* hw16   = (unsigned short*)alloc((size_t)20096 * 512 * 2);
    unsigned short* hA     = (unsigned short*)alloc((size_t)40192 * 256 * 2);
    unsigned short* hB     = (unsigned short*)alloc((size_t)40192 * 256 * 2);
    float* Tf  = (float*)alloc((size_t)512 * 512 * 4);
    unsigned short* Ub = (unsigned short*)alloc((size_t)512 * 512 * 2);
    unsigned short* WT = (unsigned short*)alloc((size_t)2 * 256 * 256 * 2);
    float* cvec = (float*)alloc(512 * 4);
    float* cb2  = (float*)alloc(512 * 4);
    float* pout = (float*)alloc((size_t)8 * NN * 4);
    int*   cnt  = (int*)alloc((size_t)NN * 4);
    int*   csr  = (int*)alloc((size_t)NN * 64 * 4);

    hipMemsetAsync(cnt, 0, (size_t)NN * 4, stream);

    const int cntBlks = (E + 255) / 256;
    prep<<<cntBlks + 64 + 2512 + 32 + 128, 256, 0, stream>>>(
        nodes, x, gcn_W, bp, eidx, eidx + E, nsum16, WT, Tf, cvec, cnt, csr, E);
    mid<<<66, 256, 0, stream>>>(Tf, Wp, gcn_W, cvec, Ub, cb2);

    // hw1[node,(b,s)] = (nsum @ U^T + cb2) * dinv[node]
    mgemm<<<dim3(8, 157), 256, 0, stream>>>(nsum16, Ub, 512, 512, 1, cb2, cnt, hw16);

    aggregate_x<<<5000, 256, 0, stream>>>(hw16, cnt, csr, gcn_b + 0, hA, w_bp, pout);
    mgemm<<<dim3(4, 314), 256, 0, stream>>>(hA, WT, 256, 256, 2, nullptr, cnt, hw16);
    aggregate_x<<<5000, 256, 0, stream>>>(hw16, cnt, csr, gcn_b + 256, hB, w_bp, pout);
    mgemm<<<dim3(4, 314), 256, 0, stream>>>(hB, WT + 65536, 256, 256, 2, nullptr, cnt, hw16);
    aggregate_x<<<5000, 256, 0, stream>>>(hw16, cnt, csr, gcn_b + 512, nullptr, w_bp, pout);
    finishk<<<157, 256, 0, stream>>>(pout, b_bp, (float*)d_out);
}

// Round 12
// 348.101 us; speedup vs baseline: 1.1636x; 1.1636x over previous
//
#include <hip/hip_runtime.h>
#include <cstddef>
#include <cstdint>

#define NN 20000

typedef short frag16 __attribute__((ext_vector_type(8)));
typedef float f32x4 __attribute__((ext_vector_type(4)));

__device__ inline unsigned short f32_to_bf16(float f) {
    uint32_t u = __float_as_uint(f);
    u += 0x7FFFu + ((u >> 16) & 1u);
    return (unsigned short)(u >> 16);
}

__device__ inline void dec8_add(uint4 v, float* a) {
    a[0] += __uint_as_float(v.x << 16);
    a[1] += __uint_as_float(v.x & 0xffff0000u);
    a[2] += __uint_as_float(v.y << 16);
    a[3] += __uint_as_float(v.y & 0xffff0000u);
    a[4] += __uint_as_float(v.z << 16);
    a[5] += __uint_as_float(v.z & 0xffff0000u);
    a[6] += __uint_as_float(v.w << 16);
    a[7] += __uint_as_float(v.w & 0xffff0000u);
}

// ===================== fused prep (R4 layout: measured best) ======================
__global__ __launch_bounds__(256) void prep(
    const float* __restrict__ nodes, const float* __restrict__ x,
    const float* __restrict__ gcn_W, const float* __restrict__ bp,
    const int* __restrict__ src, const int* __restrict__ dst,
    unsigned short* __restrict__ nsum16, unsigned short* __restrict__ WT,
    float* __restrict__ Tf, float* __restrict__ cvec,
    int* __restrict__ cnt, int* __restrict__ csr, int E)
{
    __shared__ __align__(16) char shmem[8704];
    const int blk = blockIdx.x, tid = threadIdx.x;

    if (blk < 64) {                          // ---- T section (fp32, dbuf loads) ----
        float* As = (float*)shmem;
        float* Bs = As + 1024;
        int t = blk;
        int b = t >> 5, rem = t & 31;
        int s0 = (rem >> 3) * 64, f0 = (rem & 7) * 64;
        const float* W1 = gcn_W;
        const float* xb = x + (size_t)b * 256 * 512;
        int kk = tid >> 4, c4 = (tid & 15) << 2;
        int tm = tid >> 4, tn = tid & 15;
        float acc[4][4] = {};
        float4 av = *(const float4*)(W1 + (size_t)kk * 256 + s0 + c4);
        float4 bv = *(const float4*)(xb + (size_t)kk * 512 + f0 + c4);
        for (int k0 = 0; k0 < 256; k0 += 16) {
            __syncthreads();
            *(float4*)&As[kk * 64 + c4] = av;
            *(float4*)&Bs[kk * 64 + c4] = bv;
            __syncthreads();
            if (k0 + 16 < 256) {             // prefetch next tile under compute
                av = *(const float4*)(W1 + (size_t)(k0 + 16 + kk) * 256 + s0 + c4);
                bv = *(const float4*)(xb + (size_t)(k0 + 16 + kk) * 512 + f0 + c4);
            }
            #pragma unroll
            for (int k = 0; k < 16; ++k) {
                float a[4], bb[4];
                *(float4*)a  = *(const float4*)&As[k * 64 + (tm << 2)];
                *(float4*)bb = *(const float4*)&Bs[k * 64 + (tn << 2)];
                #pragma unroll
                for (int i = 0; i < 4; ++i)
                    #pragma unroll
                    for (int j = 0; j < 4; ++j) acc[i][j] += a[i] * bb[j];
            }
        }
        #pragma unroll
        for (int i = 0; i < 4; ++i) {
            int row = b * 256 + s0 + (tm << 2) + i;
            *(float4*)(Tf + (size_t)row * 512 + f0 + (tn << 2)) =
                make_float4(acc[i][0], acc[i][1], acc[i][2], acc[i][3]);
        }
    } else if (blk < 96) {                   // ---- WT transpose (l=1,2) ----
        unsigned short (*tsh)[68] = (unsigned short(*)[68])shmem;
        int t = blk - 64;
        int l = t >> 4, rem = t & 15;
        int c0 = (rem & 3) * 64, r0 = (rem >> 2) * 64;
        const float* inp = gcn_W + (size_t)(l + 1) * 65536;
        unsigned short* outp = WT + (size_t)l * 65536;
        int tx = tid & 15, ty = tid >> 4;
        #pragma unroll
        for (int rr = 0; rr < 4; ++rr) {
            int r = ty * 4 + rr;
            float4 v = *(const float4*)(inp + (size_t)(r0 + r) * 256 + c0 + tx * 4);
            tsh[tx * 4 + 0][r] = f32_to_bf16(v.x);
            tsh[tx * 4 + 1][r] = f32_to_bf16(v.y);
            tsh[tx * 4 + 2][r] = f32_to_bf16(v.z);
            tsh[tx * 4 + 3][r] = f32_to_bf16(v.w);
        }
        __syncthreads();
        #pragma unroll
        for (int cc = 0; cc < 4; ++cc) {
            int c = ty * 4 + cc;
            ushort4 o = *(ushort4*)&tsh[c][tx * 4];
            *(ushort4*)(outp + (size_t)(c0 + c) * 256 + r0 + tx * 4) = o;
        }
    } else if (blk < 224) {                  // ---- cvec ----
        int row = (blk - 96) * 4 + (tid >> 6);
        int lane = tid & 63;
        const float* xr = x + (size_t)row * 512;
        float s = 0.f;
        #pragma unroll
        for (int k = 0; k < 512; k += 64) s += xr[k + lane] * bp[k + lane];
        #pragma unroll
        for (int off = 32; off; off >>= 1) s += __shfl_down(s, off);
        if (lane == 0) cvec[row] = 2.0f * s;
    } else if (blk < 224 + 2512) {           // ---- nsum, 16 shorts/thread ----
        int g = (blk - 224) * 256 + tid;
        int n = g >> 5, c = (g & 31) << 4;
        uint4 o0, o1;
        if (n < NN) {
            const float* r0 = nodes + (size_t)n * 1024 + c;
            const float* r1 = r0 + 512;
            float4 a0 = *(const float4*)(r0 + 0),  a1 = *(const float4*)(r0 + 4);
            float4 a2 = *(const float4*)(r0 + 8),  a3 = *(const float4*)(r0 + 12);
            float4 b0 = *(const float4*)(r1 + 0),  b1 = *(const float4*)(r1 + 4);
            float4 b2 = *(const float4*)(r1 + 8),  b3 = *(const float4*)(r1 + 12);
            o0.x = ((uint32_t)f32_to_bf16(a0.y + b0.y) << 16) | f32_to_bf16(a0.x + b0.x);
            o0.y = ((uint32_t)f32_to_bf16(a0.w + b0.w) << 16) | f32_to_bf16(a0.z + b0.z);
            o0.z = ((uint32_t)f32_to_bf16(a1.y + b1.y) << 16) | f32_to_bf16(a1.x + b1.x);
            o0.w = ((uint32_t)f32_to_bf16(a1.w + b1.w) << 16) | f32_to_bf16(a1.z + b1.z);
            o1.x = ((uint32_t)f32_to_bf16(a2.y + b2.y) << 16) | f32_to_bf16(a2.x + b2.x);
            o1.y = ((uint32_t)f32_to_bf16(a2.w + b2.w) << 16) | f32_to_bf16(a2.z + b2.z);
            o1.z = ((uint32_t)f32_to_bf16(a3.y + b3.y) << 16) | f32_to_bf16(a3.x + b3.x);
            o1.w = ((uint32_t)f32_to_bf16(a3.w + b3.w) << 16) | f32_to_bf16(a3.z + b3.z);
        } else {
            o0 = make_uint4(0, 0, 0, 0); o1 = o0;
        }
        *(uint4*)(nsum16 + (size_t)n * 512 + c) = o0;
        *(uint4*)(nsum16 + (size_t)n * 512 + c + 8) = o1;
    } else {                                 // ---- count + CSR fill ----
        int e = (blk - 2736) * 256 + tid;
        if (e < E) {
            int d = dst[e];
            int pos = atomicAdd(&cnt[d], 1);
            if (pos < 64) csr[(d << 6) + pos] = src[e];
        }
    }
}

// ===================== mid: U = T @ Wp (bf16 out) + cb2 = W1^T . cvec ==============
__global__ __launch_bounds__(256) void mid(
    const float* __restrict__ Tf, const float* __restrict__ Wp,
    const float* __restrict__ gcn_W, const float* __restrict__ cvec,
    unsigned short* __restrict__ Ub, float* __restrict__ cb2)
{
    const int blk = blockIdx.x, tid = threadIdx.x;
    if (blk >= 64) {
        int idx = (blk - 64) * 256 + tid;
        int b = idx >> 8, s = idx & 255;
        float sum = 0.f;
        for (int sp = 0; sp < 256; ++sp)
            sum += gcn_W[(size_t)sp * 256 + s] * cvec[b * 256 + sp];
        cb2[idx] = sum;
        return;
    }
    __shared__ float As[16][68];
    __shared__ float Bs[16][64];
    int bm = (blk >> 3) * 64, bn = (blk & 7) * 64;
    int arow = tid >> 2, acol = (tid & 3) << 2;
    int brow = tid >> 4, bcol = (tid & 15) << 2;
    int tm = tid >> 4, tn = tid & 15;
    float acc[4][4] = {};
    float4 av = *(const float4*)(Tf + (size_t)(bm + arow) * 512 + acol);
    float4 bv = *(const float4*)(Wp + (size_t)brow * 512 + bn + bcol);
    for (int k0 = 0; k0 < 512; k0 += 16) {
        __syncthreads();
        As[acol + 0][arow] = av.x; As[acol + 1][arow] = av.y;
        As[acol + 2][arow] = av.z; As[acol + 3][arow] = av.w;
        *(float4*)&Bs[brow][bcol] = bv;
        __syncthreads();
        if (k0 + 16 < 512) {                 // prefetch next tile under compute
            av = *(const float4*)(Tf + (size_t)(bm + arow) * 512 + k0 + 16 + acol);
            bv = *(const float4*)(Wp + (size_t)(k0 + 16 + brow) * 512 + bn + bcol);
        }
        #pragma unroll
        for (int k = 0; k < 16; ++k) {
            float a[4], b[4];
            *(float4*)a = *(const float4*)&As[k][tm << 2];
            *(float4*)b = *(const float4*)&Bs[k][tn << 2];
            #pragma unroll
            for (int i = 0; i < 4; ++i)
                #pragma unroll
                for (int j = 0; j < 4; ++j) acc[i][j] += a[i] * b[j];
        }
    }
    #pragma unroll
    for (int i = 0; i < 4; ++i) {
        int row = bm + (tm << 2) + i;
        ushort4 o;
        o.x = f32_to_bf16(acc[i][0]); o.y = f32_to_bf16(acc[i][1]);
        o.z = f32_to_bf16(acc[i][2]); o.w = f32_to_bf16(acc[i][3]);
        *(ushort4*)(Ub + (size_t)row * 512 + bn + (tn << 2)) = o;
    }
}

// ===================== bf16 MFMA GEMM (128x64 tile; R4 skeleton) ==================
// C = A[M,K] @ BT[N,K]^T, bf16 in/out, fp32 accum. Single-buffer gload_lds staging
// (R4-proven). Tile halved 128x128 -> 128x64: grids 628/1256 blocks -> ~5 resident
// blocks/CU (R8 PMC: 23% occupancy was GRID-limited) so barrier drains overlap
// across co-resident blocks. LDS 12KB.
// mode 1: C[m*512+n] = (acc + cb2[n]) * rsqrt(cnt[m]+1)   (m = node)
// mode 2: N=256; b2 = m>=NN, node=m-b2*NN; C[node*512+(b2<<8)+n] = acc*rsqrt(cnt+1)
__global__ __launch_bounds__(256) void mgemm(
    const unsigned short* __restrict__ A, const unsigned short* __restrict__ BT,
    int K, int N, int mode,
    const float* __restrict__ cb2, const int* __restrict__ cnt,
    unsigned short* __restrict__ C)
{
    __shared__ __align__(16) unsigned short As[128 * 32];
    __shared__ __align__(16) unsigned short Bs[64 * 32];
    const int bm = blockIdx.y * 128, bn = blockIdx.x * 64;
    const int tid = threadIdx.x;
    const int lane = tid & 63, w = tid >> 6;
    const int wm = (w >> 1) << 6, wn = (w & 1) << 5;
    const int r16 = lane & 15, q16 = lane >> 4;

    f32x4 acc[4][2] = {};

    for (int k0 = 0; k0 < K; k0 += 32) {
        __syncthreads();
        {   // A tile 128x32: 512 slots of 16B, 2 per thread
            #pragma unroll
            for (int t = 0; t < 2; ++t) {
                int c = t * 256 + w * 64 + lane;
                int row = c >> 2, col = (c & 3) << 3;
                __builtin_amdgcn_global_load_lds(
                    (const __attribute__((address_space(1))) void*)(A + (size_t)(bm + row) * K + k0 + col),
                    (__attribute__((address_space(3))) void*)(As + (size_t)c * 8),
                    16, 0, 0);
            }
            // B tile 64x32: 256 slots of 16B, 1 per thread
            int c = w * 64 + lane;
            int row = c >> 2, col = (c & 3) << 3;
            __builtin_amdgcn_global_load_lds(
                (const __attribute__((address_space(1))) void*)(BT + (size_t)(bn + row) * K + k0 + col),
                (__attribute__((address_space(3))) void*)(Bs + (size_t)c * 8),
                16, 0, 0);
        }
        __syncthreads();
        frag16 af[4], bf[2];
        #pragma unroll
        for (int i = 0; i < 4; ++i)
            af[i] = *(const frag16*)(As + ((wm + i * 16 + r16) << 5) + (q16 << 3));
        #pragma unroll
        for (int j = 0; j < 2; ++j)
            bf[j] = *(const frag16*)(Bs + ((wn + j * 16 + r16) << 5) + (q16 << 3));
        #pragma unroll
        for (int i = 0; i < 4; ++i)
            #pragma unroll
            for (int j = 0; j < 2; ++j)
                acc[i][j] = __builtin_amdgcn_mfma_f32_16x16x32_bf16(af[i], bf[j], acc[i][j], 0, 0, 0);
    }

    // C/D layout: col = lane&15 (r16), row = q16*4 + reg
    #pragma unroll
    for (int i = 0; i < 4; ++i) {
        #pragma unroll
        for (int rg = 0; rg < 4; ++rg) {
            int m = bm + wm + i * 16 + (q16 << 2) + rg;
            float sc;
            int b2 = 0, node = m;
            if (mode == 1) {
                int nc = m > NN - 1 ? NN - 1 : m;
                sc = rsqrtf((float)cnt[nc] + 1.0f);
            } else {
                b2 = m >= NN;
                node = m - b2 * NN;
                int nc = node > NN - 1 ? NN - 1 : node;
                sc = rsqrtf((float)cnt[nc] + 1.0f);
                if (node > 20095) node = 20095;
            }
            #pragma unroll
            for (int j = 0; j < 2; ++j) {
                int n = bn + wn + j * 16 + r16;
                if (mode == 1) {
                    float v = (acc[i][j][rg] + cb2[n]) * sc;
                    C[(size_t)m * 512 + n] = f32_to_bf16(v);
                } else {
                    float v = acc[i][j][rg] * sc;
                    C[(size_t)node * 512 + (b2 << 8) + n] = f32_to_bf16(v);
                }
            }
        }
    }
}

// ===================== GCN aggregation (R4: XCD-sliced, LDS-csr, 8-deep) ==========
__global__ __launch_bounds__(256) void aggregate_x(
    const unsigned short* __restrict__ hw, const int* __restrict__ cnt,
    const int* __restrict__ csr, const float* __restrict__ bias,
    unsigned short* __restrict__ hout,
    const float* __restrict__ w_bp, float* __restrict__ pout)
{
    __shared__ int sidx[2048];
    __shared__ int sdeg[32];
    const int s  = blockIdx.x & 7;             // slice 0..7
    const int nb = blockIdx.x >> 3;            // node block 0..624
    const int tid = threadIdx.x;
    const int g = tid >> 3;                    // group 0..31
    const int j = tid & 7;                     // lane in group
    const int n = nb * 32 + g;                 // node 0..19999

    {   // coalesced CSR block preload: 2048 ints, 8 per thread
        const int4* cp = (const int4*)(csr + ((size_t)nb << 11));
        int4 v0 = cp[tid * 2];
        int4 v1 = cp[tid * 2 + 1];
        *(int4*)&sidx[tid * 8]     = v0;
        *(int4*)&sidx[tid * 8 + 4] = v1;
        if (tid < 32) {
            int d = cnt[nb * 32 + tid];
            sdeg[tid] = d > 64 ? 64 : d;
        }
    }
    __syncthreads();

    const unsigned short* rowp = hw + (s << 6) + (j << 3);  // 16B/lane, 128B/group
    const int deg = sdeg[g];
    const int* gi = sidx + (g << 6);

    float acc[8] = {};
    dec8_add(*(const uint4*)(rowp + (size_t)n * 512), acc);   // self loop

    int e = 0;
    for (; e + 8 <= deg; e += 8) {
        int s0 = gi[e + 0], s1 = gi[e + 1], s2 = gi[e + 2], s3 = gi[e + 3];
        int s4 = gi[e + 4], s5 = gi[e + 5], s6 = gi[e + 6], s7 = gi[e + 7];
        uint4 u0 = *(const uint4*)(rowp + (size_t)s0 * 512);
        uint4 u1 = *(const uint4*)(rowp + (size_t)s1 * 512);
        uint4 u2 = *(const uint4*)(rowp + (size_t)s2 * 512);
        uint4 u3 = *(const uint4*)(rowp + (size_t)s3 * 512);
        uint4 u4 = *(const uint4*)(rowp + (size_t)s4 * 512);
        uint4 u5 = *(const uint4*)(rowp + (size_t)s5 * 512);
        uint4 u6 = *(const uint4*)(rowp + (size_t)s6 * 512);
        uint4 u7 = *(const uint4*)(rowp + (size_t)s7 * 512);
        dec8_add(u0, acc); dec8_add(u1, acc); dec8_add(u2, acc); dec8_add(u3, acc);
        dec8_add(u4, acc); dec8_add(u5, acc); dec8_add(u6, acc); dec8_add(u7, acc);
    }
    for (; e < deg; ++e) {
        dec8_add(*(const uint4*)(rowp + (size_t)gi[e] * 512), acc);
    }

    float dn = rsqrtf((float)deg + 1.0f);
    int colb = ((s & 3) << 6) + (j << 3);      // column within batch, 0..248
    float bl[8];
    *(float4*)&bl[0] = *(const float4*)(bias + colb);
    *(float4*)&bl[4] = *(const float4*)(bias + colb + 4);
    float v[8];
    #pragma unroll
    for (int t = 0; t < 8; ++t) {
        v[t] = fmaf(dn, acc[t], bl[t]);
        v[t] = v[t] > 0.f ? v[t] : 0.01f * v[t];
    }

    if (hout) {
        int b = s >> 2;
        uint4 o;
        o.x = ((uint32_t)f32_to_bf16(v[1]) << 16) | f32_to_bf16(v[0]);
        o.y = ((uint32_t)f32_to_bf16(v[3]) << 16) | f32_to_bf16(v[2]);
        o.z = ((uint32_t)f32_to_bf16(v[5]) << 16) | f32_to_bf16(v[4]);
        o.w = ((uint32_t)f32_to_bf16(v[7]) << 16) | f32_to_bf16(v[6]);
        *(uint4*)(hout + ((size_t)(b * NN + n)) * 256 + colb) = o;
    } else {
        float w4[8];
        *(float4*)&w4[0] = *(const float4*)(w_bp + colb);
        *(float4*)&w4[4] = *(const float4*)(w_bp + colb + 4);
        float sum = 0.f;
        #pragma unroll
        for (int t = 0; t < 8; ++t) sum += v[t] * w4[t];
        sum += __shfl_xor(sum, 1);
        sum += __shfl_xor(sum, 2);
        sum += __shfl_xor(sum, 4);
        if (j == 0) pout[s * NN + n] = sum;
    }
}

// sum the 4 slice partials per (batch, node) and add bias
__global__ __launch_bounds__(256) void finishk(
    const float* __restrict__ pout, const float* __restrict__ b_bp,
    float* __restrict__ out)
{
    int i = blockIdx.x * 256 + threadIdx.x;
    if (i < 2 * NN) {
        int b = i >= NN;
        int n = i - b * NN;
        const float* p = pout + b * 4 * NN + n;
        out[i] = b_bp[0] + p[0] + p[NN] + p[2 * NN] + p[3 * NN];
    }
}

extern "C" void kernel_launch(void* const* d_in, const int* in_sizes, int n_in,
                              void* d_out, int out_size, void* d_ws, size_t ws_size,
                              hipStream_t stream) {
    const float* x     = (const float*)d_in[0];
    const float* nodes = (const float*)d_in[1];
    const int*   eidx  = (const int*)d_in[2];
    const float* Wp    = (const float*)d_in[3];
    const float* bp    = (const float*)d_in[4];
    const float* gcn_W = (const float*)d_in[5];
    const float* gcn_b = (const float*)d_in[6];
    const float* w_bp  = (const float*)d_in[7];
    const float* b_bp  = (const float*)d_in[8];
    const int E = in_sizes[2] / 2;

    char* w = (char*)d_ws;
    auto alloc = [&](size_t bytes) { char* p = w; w += (bytes + 255) & ~(size_t)255; return p; };
    unsigned short* nsum16 = (unsigned short*)alloc((size_t)20096 * 512 * 2);
    unsigned short* hw16   = (unsigned short*)alloc((size_t)20096 * 512 * 2);
    unsigned short* hA     = (unsigned short*)alloc((size_t)40192 * 256 * 2);
    unsigned short* hB     = (unsigned short*)alloc((size_t)40192 * 256 * 2);
    float* Tf  = (float*)alloc((size_t)512 * 512 * 4);
    unsigned short* Ub = (unsigned short*)alloc((size_t)512 * 512 * 2);
    unsigned short* WT = (unsigned short*)alloc((size_t)2 * 256 * 256 * 2);
    float* cvec = (float*)alloc(512 * 4);
    float* cb2  = (float*)alloc(512 * 4);
    float* pout = (float*)alloc((size_t)8 * NN * 4);
    int*   cnt  = (int*)alloc((size_t)NN * 4);
    int*   csr  = (int*)alloc((size_t)NN * 64 * 4);

    hipMemsetAsync(cnt, 0, (size_t)NN * 4, stream);

    const int cntBlks = (E + 255) / 256;
    prep<<<cntBlks + 64 + 2512 + 32 + 128, 256, 0, stream>>>(
        nodes, x, gcn_W, bp, eidx, eidx + E, nsum16, WT, Tf, cvec, cnt, csr, E);
    mid<<<66, 256, 0, stream>>>(Tf, Wp, gcn_W, cvec, Ub, cb2);

    // hw1[node,(b,s)] = (nsum @ U^T + cb2) * dinv[node]
    mgemm<<<dim3(8, 157), 256, 0, stream>>>(nsum16, Ub, 512, 512, 1, cb2, cnt, hw16);

    aggregate_x<<<5000, 256, 0, stream>>>(hw16, cnt, csr, gcn_b + 0, hA, w_bp, pout);
    mgemm<<<dim3(4, 314), 256, 0, stream>>>(hA, WT, 256, 256, 2, nullptr, cnt, hw16);
    aggregate_x<<<5000, 256, 0, stream>>>(hw16, cnt, csr, gcn_b + 256, hB, w_bp, pout);
    mgemm<<<dim3(4, 314), 256, 0, stream>>>(hB, WT + 65536, 256, 256, 2, nullptr, cnt, hw16);
    aggregate_x<<<5000, 256, 0, stream>>>(hw16, cnt, csr, gcn_b + 512, nullptr, w_bp, pout);
    finishk<<<157, 256, 0, stream>>>(pout, b_bp, (float*)d_out);
}

// Round 13
// 337.423 us; speedup vs baseline: 1.2005x; 1.0316x over previous
//
#include <hip/hip_runtime.h>
#include <cstddef>
#include <cstdint>

#define NN 20000

typedef short frag16 __attribute__((ext_vector_type(8)));
typedef float f32x4 __attribute__((ext_vector_type(4)));

__device__ inline unsigned short f32_to_bf16(float f) {
    uint32_t u = __float_as_uint(f);
    u += 0x7FFFu + ((u >> 16) & 1u);
    return (unsigned short)(u >> 16);
}

__device__ inline void dec8_add(uint4 v, float* a) {
    a[0] += __uint_as_float(v.x << 16);
    a[1] += __uint_as_float(v.x & 0xffff0000u);
    a[2] += __uint_as_float(v.y << 16);
    a[3] += __uint_as_float(v.y & 0xffff0000u);
    a[4] += __uint_as_float(v.z << 16);
    a[5] += __uint_as_float(v.z & 0xffff0000u);
    a[6] += __uint_as_float(v.w << 16);
    a[7] += __uint_as_float(v.w & 0xffff0000u);
}

// ===================== fused prep (R4 layout: measured best) ======================
__global__ __launch_bounds__(256) void prep(
    const float* __restrict__ nodes, const float* __restrict__ x,
    const float* __restrict__ gcn_W, const float* __restrict__ bp,
    const int* __restrict__ src, const int* __restrict__ dst,
    unsigned short* __restrict__ nsum16, unsigned short* __restrict__ WT,
    float* __restrict__ Tf, float* __restrict__ cvec,
    int* __restrict__ cnt, int* __restrict__ csr, int E)
{
    __shared__ __align__(16) char shmem[8704];
    const int blk = blockIdx.x, tid = threadIdx.x;

    if (blk < 64) {                          // ---- T section (fp32, dbuf loads) ----
        float* As = (float*)shmem;
        float* Bs = As + 1024;
        int t = blk;
        int b = t >> 5, rem = t & 31;
        int s0 = (rem >> 3) * 64, f0 = (rem & 7) * 64;
        const float* W1 = gcn_W;
        const float* xb = x + (size_t)b * 256 * 512;
        int kk = tid >> 4, c4 = (tid & 15) << 2;
        int tm = tid >> 4, tn = tid & 15;
        float acc[4][4] = {};
        float4 av = *(const float4*)(W1 + (size_t)kk * 256 + s0 + c4);
        float4 bv = *(const float4*)(xb + (size_t)kk * 512 + f0 + c4);
        for (int k0 = 0; k0 < 256; k0 += 16) {
            __syncthreads();
            *(float4*)&As[kk * 64 + c4] = av;
            *(float4*)&Bs[kk * 64 + c4] = bv;
            __syncthreads();
            if (k0 + 16 < 256) {             // prefetch next tile under compute
                av = *(const float4*)(W1 + (size_t)(k0 + 16 + kk) * 256 + s0 + c4);
                bv = *(const float4*)(xb + (size_t)(k0 + 16 + kk) * 512 + f0 + c4);
            }
            #pragma unroll
            for (int k = 0; k < 16; ++k) {
                float a[4], bb[4];
                *(float4*)a  = *(const float4*)&As[k * 64 + (tm << 2)];
                *(float4*)bb = *(const float4*)&Bs[k * 64 + (tn << 2)];
                #pragma unroll
                for (int i = 0; i < 4; ++i)
                    #pragma unroll
                    for (int j = 0; j < 4; ++j) acc[i][j] += a[i] * bb[j];
            }
        }
        #pragma unroll
        for (int i = 0; i < 4; ++i) {
            int row = b * 256 + s0 + (tm << 2) + i;
            *(float4*)(Tf + (size_t)row * 512 + f0 + (tn << 2)) =
                make_float4(acc[i][0], acc[i][1], acc[i][2], acc[i][3]);
        }
    } else if (blk < 96) {                   // ---- WT transpose (l=1,2) ----
        unsigned short (*tsh)[68] = (unsigned short(*)[68])shmem;
        int t = blk - 64;
        int l = t >> 4, rem = t & 15;
        int c0 = (rem & 3) * 64, r0 = (rem >> 2) * 64;
        const float* inp = gcn_W + (size_t)(l + 1) * 65536;
        unsigned short* outp = WT + (size_t)l * 65536;
        int tx = tid & 15, ty = tid >> 4;
        #pragma unroll
        for (int rr = 0; rr < 4; ++rr) {
            int r = ty * 4 + rr;
            float4 v = *(const float4*)(inp + (size_t)(r0 + r) * 256 + c0 + tx * 4);
            tsh[tx * 4 + 0][r] = f32_to_bf16(v.x);
            tsh[tx * 4 + 1][r] = f32_to_bf16(v.y);
            tsh[tx * 4 + 2][r] = f32_to_bf16(v.z);
            tsh[tx * 4 + 3][r] = f32_to_bf16(v.w);
        }
        __syncthreads();
        #pragma unroll
        for (int cc = 0; cc < 4; ++cc) {
            int c = ty * 4 + cc;
            ushort4 o = *(ushort4*)&tsh[c][tx * 4];
            *(ushort4*)(outp + (size_t)(c0 + c) * 256 + r0 + tx * 4) = o;
        }
    } else if (blk < 224) {                  // ---- cvec ----
        int row = (blk - 96) * 4 + (tid >> 6);
        int lane = tid & 63;
        const float* xr = x + (size_t)row * 512;
        float s = 0.f;
        #pragma unroll
        for (int k = 0; k < 512; k += 64) s += xr[k + lane] * bp[k + lane];
        #pragma unroll
        for (int off = 32; off; off >>= 1) s += __shfl_down(s, off);
        if (lane == 0) cvec[row] = 2.0f * s;
    } else if (blk < 224 + 2512) {           // ---- nsum, 16 shorts/thread ----
        int g = (blk - 224) * 256 + tid;
        int n = g >> 5, c = (g & 31) << 4;
        uint4 o0, o1;
        if (n < NN) {
            const float* r0 = nodes + (size_t)n * 1024 + c;
            const float* r1 = r0 + 512;
            float4 a0 = *(const float4*)(r0 + 0),  a1 = *(const float4*)(r0 + 4);
            float4 a2 = *(const float4*)(r0 + 8),  a3 = *(const float4*)(r0 + 12);
            float4 b0 = *(const float4*)(r1 + 0),  b1 = *(const float4*)(r1 + 4);
            float4 b2 = *(const float4*)(r1 + 8),  b3 = *(const float4*)(r1 + 12);
            o0.x = ((uint32_t)f32_to_bf16(a0.y + b0.y) << 16) | f32_to_bf16(a0.x + b0.x);
            o0.y = ((uint32_t)f32_to_bf16(a0.w + b0.w) << 16) | f32_to_bf16(a0.z + b0.z);
            o0.z = ((uint32_t)f32_to_bf16(a1.y + b1.y) << 16) | f32_to_bf16(a1.x + b1.x);
            o0.w = ((uint32_t)f32_to_bf16(a1.w + b1.w) << 16) | f32_to_bf16(a1.z + b1.z);
            o1.x = ((uint32_t)f32_to_bf16(a2.y + b2.y) << 16) | f32_to_bf16(a2.x + b2.x);
            o1.y = ((uint32_t)f32_to_bf16(a2.w + b2.w) << 16) | f32_to_bf16(a2.z + b2.z);
            o1.z = ((uint32_t)f32_to_bf16(a3.y + b3.y) << 16) | f32_to_bf16(a3.x + b3.x);
            o1.w = ((uint32_t)f32_to_bf16(a3.w + b3.w) << 16) | f32_to_bf16(a3.z + b3.z);
        } else {
            o0 = make_uint4(0, 0, 0, 0); o1 = o0;
        }
        *(uint4*)(nsum16 + (size_t)n * 512 + c) = o0;
        *(uint4*)(nsum16 + (size_t)n * 512 + c + 8) = o1;
    } else {                                 // ---- count + CSR fill ----
        int e = (blk - 2736) * 256 + tid;
        if (e < E) {
            int d = dst[e];
            int pos = atomicAdd(&cnt[d], 1);
            if (pos < 64) csr[(d << 6) + pos] = src[e];
        }
    }
}

// ===================== mid: U = T @ Wp (bf16 out) + cb2 = W1^T . cvec ==============
__global__ __launch_bounds__(256) void mid(
    const float* __restrict__ Tf, const float* __restrict__ Wp,
    const float* __restrict__ gcn_W, const float* __restrict__ cvec,
    unsigned short* __restrict__ Ub, float* __restrict__ cb2)
{
    const int blk = blockIdx.x, tid = threadIdx.x;
    if (blk >= 64) {
        int idx = (blk - 64) * 256 + tid;
        int b = idx >> 8, s = idx & 255;
        float sum = 0.f;
        for (int sp = 0; sp < 256; ++sp)
            sum += gcn_W[(size_t)sp * 256 + s] * cvec[b * 256 + sp];
        cb2[idx] = sum;
        return;
    }
    __shared__ float As[16][68];
    __shared__ float Bs[16][64];
    int bm = (blk >> 3) * 64, bn = (blk & 7) * 64;
    int arow = tid >> 2, acol = (tid & 3) << 2;
    int brow = tid >> 4, bcol = (tid & 15) << 2;
    int tm = tid >> 4, tn = tid & 15;
    float acc[4][4] = {};
    float4 av = *(const float4*)(Tf + (size_t)(bm + arow) * 512 + acol);
    float4 bv = *(const float4*)(Wp + (size_t)brow * 512 + bn + bcol);
    for (int k0 = 0; k0 < 512; k0 += 16) {
        __syncthreads();
        As[acol + 0][arow] = av.x; As[acol + 1][arow] = av.y;
        As[acol + 2][arow] = av.z; As[acol + 3][arow] = av.w;
        *(float4*)&Bs[brow][bcol] = bv;
        __syncthreads();
        if (k0 + 16 < 512) {                 // prefetch next tile under compute
            av = *(const float4*)(Tf + (size_t)(bm + arow) * 512 + k0 + 16 + acol);
            bv = *(const float4*)(Wp + (size_t)(k0 + 16 + brow) * 512 + bn + bcol);
        }
        #pragma unroll
        for (int k = 0; k < 16; ++k) {
            float a[4], b[4];
            *(float4*)a = *(const float4*)&As[k][tm << 2];
            *(float4*)b = *(const float4*)&Bs[k][tn << 2];
            #pragma unroll
            for (int i = 0; i < 4; ++i)
                #pragma unroll
                for (int j = 0; j < 4; ++j) acc[i][j] += a[i] * b[j];
        }
    }
    #pragma unroll
    for (int i = 0; i < 4; ++i) {
        int row = bm + (tm << 2) + i;
        ushort4 o;
        o.x = f32_to_bf16(acc[i][0]); o.y = f32_to_bf16(acc[i][1]);
        o.z = f32_to_bf16(acc[i][2]); o.w = f32_to_bf16(acc[i][3]);
        *(ushort4*)(Ub + (size_t)row * 512 + bn + (tn << 2)) = o;
    }
}

// ===================== bf16 MFMA GEMM (128x128, dbuf + counted vmcnt) =============
// C = A[M,K] @ BT[N,K]^T, bf16 in/out, fp32 accum. T4 pipeline: stage tile t+1 into
// the other LDS buffer, then `s_waitcnt vmcnt(4)` (tile t's 4 per-thread loads done,
// t+1's 4 still IN FLIGHT) + raw s_barrier. Unlike __syncthreads (vmcnt(0) drain,
// R4/R5), prefetch loads cross the barrier -> cross-XCD L2/L3 latency on freshly-
// written A overlaps with compute. Trailing s_barrier guards WAR on restage (ds_reads
// are lgkm-complete before MFMA issue).
// mode 1: C[m*512+n] = (acc + cb2[n]) * rsqrt(cnt[m]+1)   (m = node)
// mode 2: N=256; b2 = m>=NN, node=m-b2*NN; C[node*512+(b2<<8)+n] = acc*rsqrt(cnt+1)
__global__ __launch_bounds__(256) void mgemm(
    const unsigned short* __restrict__ A, const unsigned short* __restrict__ BT,
    int K, int N, int mode,
    const float* __restrict__ cb2, const int* __restrict__ cnt,
    unsigned short* __restrict__ C)
{
    __shared__ __align__(16) unsigned short As[2][128 * 32];
    __shared__ __align__(16) unsigned short Bs[2][128 * 32];
    const int bm = blockIdx.y * 128, bn = blockIdx.x * 128;
    const int tid = threadIdx.x;
    const int lane = tid & 63, w = tid >> 6;
    const int wm = (w >> 1) << 6, wn = (w & 1) << 6;
    const int r16 = lane & 15, q16 = lane >> 4;

    f32x4 acc[4][4] = {};

    auto stage = [&](int buf, int k0) {    // 4 gload_lds per thread (2 A + 2 B)
        #pragma unroll
        for (int t = 0; t < 2; ++t) {
            int c = t * 256 + w * 64 + lane;
            int row = c >> 2, col = (c & 3) << 3;
            __builtin_amdgcn_global_load_lds(
                (const __attribute__((address_space(1))) void*)(A + (size_t)(bm + row) * K + k0 + col),
                (__attribute__((address_space(3))) void*)(&As[buf][(size_t)c * 8]),
                16, 0, 0);
            __builtin_amdgcn_global_load_lds(
                (const __attribute__((address_space(1))) void*)(BT + (size_t)(bn + row) * K + k0 + col),
                (__attribute__((address_space(3))) void*)(&Bs[buf][(size_t)c * 8]),
                16, 0, 0);
        }
    };

    stage(0, 0);                            // 4 in flight
    const int nk = K >> 5;
    for (int it = 0; it < nk; ++it) {
        const int cur = it & 1;
        if (it + 1 < nk) {
            stage(cur ^ 1, (it + 1) << 5);  // +4 -> 8 in flight
            asm volatile("s_waitcnt vmcnt(4)" ::: "memory");   // cur's 4 retired
        } else {
            asm volatile("s_waitcnt vmcnt(0)" ::: "memory");
        }
        __builtin_amdgcn_s_barrier();       // cur ready block-wide (no vmcnt(0) drain)
        frag16 af[4], bf[4];
        #pragma unroll
        for (int i = 0; i < 4; ++i)
            af[i] = *(const frag16*)(&As[cur][((wm + i * 16 + r16) << 5) + (q16 << 3)]);
        #pragma unroll
        for (int j = 0; j < 4; ++j)
            bf[j] = *(const frag16*)(&Bs[cur][((wn + j * 16 + r16) << 5) + (q16 << 3)]);
        #pragma unroll
        for (int i = 0; i < 4; ++i)
            #pragma unroll
            for (int j = 0; j < 4; ++j)
                acc[i][j] = __builtin_amdgcn_mfma_f32_16x16x32_bf16(af[i], bf[j], acc[i][j], 0, 0, 0);
        __builtin_amdgcn_s_barrier();       // all reads of cur done -> restage-safe
    }

    // C/D layout: col = lane&15 (r16), row = q16*4 + reg
    #pragma unroll
    for (int i = 0; i < 4; ++i) {
        #pragma unroll
        for (int rg = 0; rg < 4; ++rg) {
            int m = bm + wm + i * 16 + (q16 << 2) + rg;
            float sc;
            int b2 = 0, node = m;
            if (mode == 1) {
                int nc = m > NN - 1 ? NN - 1 : m;
                sc = rsqrtf((float)cnt[nc] + 1.0f);
            } else {
                b2 = m >= NN;
                node = m - b2 * NN;
                int nc = node > NN - 1 ? NN - 1 : node;
                sc = rsqrtf((float)cnt[nc] + 1.0f);
                if (node > 20095) node = 20095;
            }
            #pragma unroll
            for (int j = 0; j < 4; ++j) {
                int n = bn + wn + j * 16 + r16;
                if (mode == 1) {
                    float v = (acc[i][j][rg] + cb2[n]) * sc;
                    C[(size_t)m * 512 + n] = f32_to_bf16(v);
                } else {
                    float v = acc[i][j][rg] * sc;
                    C[(size_t)node * 512 + (b2 << 8) + n] = f32_to_bf16(v);
                }
            }
        }
    }
}

// ===================== GCN aggregation (R4: XCD-sliced, LDS-csr, 8-deep) ==========
__global__ __launch_bounds__(256) void aggregate_x(
    const unsigned short* __restrict__ hw, const int* __restrict__ cnt,
    const int* __restrict__ csr, const float* __restrict__ bias,
    unsigned short* __restrict__ hout,
    const float* __restrict__ w_bp, float* __restrict__ pout)
{
    __shared__ int sidx[2048];
    __shared__ int sdeg[32];
    const int s  = blockIdx.x & 7;             // slice 0..7
    const int nb = blockIdx.x >> 3;            // node block 0..624
    const int tid = threadIdx.x;
    const int g = tid >> 3;                    // group 0..31
    const int j = tid & 7;                     // lane in group
    const int n = nb * 32 + g;                 // node 0..19999

    {   // coalesced CSR block preload: 2048 ints, 8 per thread
        const int4* cp = (const int4*)(csr + ((size_t)nb << 11));
        int4 v0 = cp[tid * 2];
        int4 v1 = cp[tid * 2 + 1];
        *(int4*)&sidx[tid * 8]     = v0;
        *(int4*)&sidx[tid * 8 + 4] = v1;
        if (tid < 32) {
            int d = cnt[nb * 32 + tid];
            sdeg[tid] = d > 64 ? 64 : d;
        }
    }
    __syncthreads();

    const unsigned short* rowp = hw + (s << 6) + (j << 3);  // 16B/lane, 128B/group
    const int deg = sdeg[g];
    const int* gi = sidx + (g << 6);

    float acc[8] = {};
    dec8_add(*(const uint4*)(rowp + (size_t)n * 512), acc);   // self loop

    int e = 0;
    for (; e + 8 <= deg; e += 8) {
        int s0 = gi[e + 0], s1 = gi[e + 1], s2 = gi[e + 2], s3 = gi[e + 3];
        int s4 = gi[e + 4], s5 = gi[e + 5], s6 = gi[e + 6], s7 = gi[e + 7];
        uint4 u0 = *(const uint4*)(rowp + (size_t)s0 * 512);
        uint4 u1 = *(const uint4*)(rowp + (size_t)s1 * 512);
        uint4 u2 = *(const uint4*)(rowp + (size_t)s2 * 512);
        uint4 u3 = *(const uint4*)(rowp + (size_t)s3 * 512);
        uint4 u4 = *(const uint4*)(rowp + (size_t)s4 * 512);
        uint4 u5 = *(const uint4*)(rowp + (size_t)s5 * 512);
        uint4 u6 = *(const uint4*)(rowp + (size_t)s6 * 512);
        uint4 u7 = *(const uint4*)(rowp + (size_t)s7 * 512);
        dec8_add(u0, acc); dec8_add(u1, acc); dec8_add(u2, acc); dec8_add(u3, acc);
        dec8_add(u4, acc); dec8_add(u5, acc); dec8_add(u6, acc); dec8_add(u7, acc);
    }
    for (; e < deg; ++e) {
        dec8_add(*(const uint4*)(rowp + (size_t)gi[e] * 512), acc);
    }

    float dn = rsqrtf((float)deg + 1.0f);
    int colb = ((s & 3) << 6) + (j << 3);      // column within batch, 0..248
    float bl[8];
    *(float4*)&bl[0] = *(const float4*)(bias + colb);
    *(float4*)&bl[4] = *(const float4*)(bias + colb + 4);
    float v[8];
    #pragma unroll
    for (int t = 0; t < 8; ++t) {
        v[t] = fmaf(dn, acc[t], bl[t]);
        v[t] = v[t] > 0.f ? v[t] : 0.01f * v[t];
    }

    if (hout) {
        int b = s >> 2;
        uint4 o;
        o.x = ((uint32_t)f32_to_bf16(v[1]) << 16) | f32_to_bf16(v[0]);
        o.y = ((uint32_t)f32_to_bf16(v[3]) << 16) | f32_to_bf16(v[2]);
        o.z = ((uint32_t)f32_to_bf16(v[5]) << 16) | f32_to_bf16(v[4]);
        o.w = ((uint32_t)f32_to_bf16(v[7]) << 16) | f32_to_bf16(v[6]);
        *(uint4*)(hout + ((size_t)(b * NN + n)) * 256 + colb) = o;
    } else {
        float w4[8];
        *(float4*)&w4[0] = *(const float4*)(w_bp + colb);
        *(float4*)&w4[4] = *(const float4*)(w_bp + colb + 4);
        float sum = 0.f;
        #pragma unroll
        for (int t = 0; t < 8; ++t) sum += v[t] * w4[t];
        sum += __shfl_xor(sum, 1);
        sum += __shfl_xor(sum, 2);
        sum += __shfl_xor(sum, 4);
        if (j == 0) pout[s * NN + n] = sum;
    }
}

// sum the 4 slice partials per (batch, node) and add bias
__global__ __launch_bounds__(256) void finishk(
    const float* __restrict__ pout, const float* __restrict__ b_bp,
    float* __restrict__ out)
{
    int i = blockIdx.x * 256 + threadIdx.x;
    if (i < 2 * NN) {
        int b = i >= NN;
        int n = i - b * NN;
        const float* p = pout + b * 4 * NN + n;
        out[i] = b_bp[0] + p[0] + p[NN] + p[2 * NN] + p[3 * NN];
    }
}

extern "C" void kernel_launch(void* const* d_in, const int* in_sizes, int n_in,
                              void* d_out, int out_size, void* d_ws, size_t ws_size,
                              hipStream_t stream) {
    const float* x     = (const float*)d_in[0];
    const float* nodes = (const float*)d_in[1];
    const int*   eidx  = (const int*)d_in[2];
    const float* Wp    = (const float*)d_in[3];
    const float* bp    = (const float*)d_in[4];
    const float* gcn_W = (const float*)d_in[5];
    const float* gcn_b = (const float*)d_in[6];
    const float* w_bp  = (const float*)d_in[7];
    const float* b_bp  = (const float*)d_in[8];
    const int E = in_sizes[2] / 2;

    char* w = (char*)d_ws;
    auto alloc = [&](size_t bytes) { char* p = w; w += (bytes + 255) & ~(size_t)255; return p; };
    unsigned short* nsum16 = (unsigned short*)alloc((size_t)20096 * 512 * 2);
    unsigned short* hw16   = (unsigned short*)alloc((size_t)20096 * 512 * 2);
    unsigned short* hA     = (unsigned short*)alloc((size_t)40192 * 256 * 2);
    unsigned short* hB     = (unsigned short*)alloc((size_t)40192 * 256 * 2);
    float* Tf  = (float*)alloc((size_t)512 * 512 * 4);
    unsigned short* Ub = (unsigned short*)alloc((size_t)512 * 512 * 2);
    unsigned short* WT = (unsigned short*)alloc((size_t)2 * 256 * 256 * 2);
    float* cvec = (float*)alloc(512 * 4);
    float* cb2  = (float*)alloc(512 * 4);
    float* pout = (float*)alloc((size_t)8 * NN * 4);
    int*   cnt  = (int*)alloc((size_t)NN * 4);
    int*   csr  = (int*)alloc((size_t)NN * 64 * 4);

    hipMemsetAsync(cnt, 0, (size_t)NN * 4, stream);

    const int cntBlks = (E + 255) / 256;
    prep<<<cntBlks + 64 + 2512 + 32 + 128, 256, 0, stream>>>(
        nodes, x, gcn_W, bp, eidx, eidx + E, nsum16, WT, Tf, cvec, cnt, csr, E);
    mid<<<66, 256, 0, stream>>>(Tf, Wp, gcn_W, cvec, Ub, cb2);

    // hw1[node,(b,s)] = (nsum @ U^T + cb2) * dinv[node]
    mgemm<<<dim3(4, 157), 256, 0, stream>>>(nsum16, Ub, 512, 512, 1, cb2, cnt, hw16);

    aggregate_x<<<5000, 256, 0, stream>>>(hw16, cnt, csr, gcn_b + 0, hA, w_bp, pout);
    mgemm<<<dim3(2, 313), 256, 0, stream>>>(hA, WT, 256, 256, 2, nullptr, cnt, hw16);
    aggregate_x<<<5000, 256, 0, stream>>>(hw16, cnt, csr, gcn_b + 256, hB, w_bp, pout);
    mgemm<<<dim3(2, 313), 256, 0, stream>>>(hB, WT + 65536, 256, 256, 2, nullptr, cnt, hw16);
    aggregate_x<<<5000, 256, 0, stream>>>(hw16, cnt, csr, gcn_b + 512, nullptr, w_bp, pout);
    finishk<<<157, 256, 0, stream>>>(pout, b_bp, (float*)d_out);
}